// Round 1
// baseline (108.628 us; speedup 1.0000x reference)
//
#include <hip/hip_runtime.h>
#include <hip/hip_bf16.h>
#include <math.h>

#define WINDOW   2048
#define STRIDE   512
#define FREQ     1024
#define FRAMES   63
#define SIG_LEN  32256
#define BATCH    64
#define M_TOTAL  4032             // BATCH*FRAMES
#define KD       1024             // decimated K (one radix-2 DIF stage)

#define BM 128
#define BN 128
#define BK 64                     // two 32-wide half-buffers

#define UV_BLOCKS    2016         // 4032*128/256
#define BASIS_BLOCKS 1024         // 2048*128/256

typedef __attribute__((ext_vector_type(8)))  short short8;    // 8 bf16
typedef __attribute__((ext_vector_type(16))) float floatx16;  // 32x32 acc

__device__ __forceinline__ ushort f2bf(float f) {
    __hip_bfloat16 h = __float2bfloat16(f);
    return *reinterpret_cast<ushort*>(&h);
}

// ---------------------------------------------------------------------------
// Fused prep, single dispatch.
// Blocks [0,2016): build U,V (radix-2 DIF of the windowed frames):
//   xw[r][n] = x[b][t*512+n-768]*hann[n] (0 out of range), r=b*63+t, n<2048
//   U[r][n] = xw[n]+xw[n+1024],  V[r][n] = xw[n]-xw[n+1024],  n<1024
//   hann identity: w[n+1024] = 1 - w[n]  (cos(th+pi) = -cos th) -> one cos.
// Blocks [2016,3040): build basis Bt2[2048][1024] bf16, K-contiguous rows:
//   row c = cls*512+g: cls0: cos(2*pi*(2g)n/2048)   cls1: cos(2*pi*(2g+1)n/2048)
//                      cls2: -sin(2*pi*(2g)n/2048)  cls3: -sin(2*pi*(2g+1)n/2048)
//   (= cos/sin of the reference phase; exact int reduction (f*n)&2047)
// ---------------------------------------------------------------------------
__global__ __launch_bounds__(256) void prep_fused(
    const float* __restrict__ x, ushort* __restrict__ U,
    ushort* __restrict__ V, ushort* __restrict__ bt) {
    const int tid = threadIdx.x;
    if (blockIdx.x < UV_BLOCKS) {
        int id = blockIdx.x * 256 + tid;               // [0, 4032*128)
        int r  = id >> 7;                              // row 0..4031
        int n0 = (id & 127) * 8;                       // n offset, mult of 8
        int b  = r / FRAMES, t = r - b * FRAMES;
        int p0 = t * STRIDE + n0 - 768;                // mult of 8
        int p1 = p0 + 1024;
        float x0[8] = {0,0,0,0,0,0,0,0}, x1[8] = {0,0,0,0,0,0,0,0};
        const float* xb = x + (size_t)b * SIG_LEN;
        if (p0 >= 0 && p0 + 8 <= SIG_LEN) {
            float4 a = *(const float4*)(xb + p0), c = *(const float4*)(xb + p0 + 4);
            x0[0]=a.x; x0[1]=a.y; x0[2]=a.z; x0[3]=a.w;
            x0[4]=c.x; x0[5]=c.y; x0[6]=c.z; x0[7]=c.w;
        }
        if (p1 >= 0 && p1 + 8 <= SIG_LEN) {
            float4 a = *(const float4*)(xb + p1), c = *(const float4*)(xb + p1 + 4);
            x1[0]=a.x; x1[1]=a.y; x1[2]=a.z; x1[3]=a.w;
            x1[4]=c.x; x1[5]=c.y; x1[6]=c.z; x1[7]=c.w;
        }
        ushort uo[8], vo[8];
        const float c0 = 6.28318530717958648f / 2048.f;
#pragma unroll
        for (int j = 0; j < 8; ++j) {
            int n = n0 + j;
            float cn = __cosf(c0 * (float)n);
            float w0 = 0.5f - 0.5f * cn;               // hann[n]
            float w1 = 0.5f + 0.5f * cn;               // hann[n+1024] = 1-hann[n]
            float a = x0[j] * w0, bb = x1[j] * w1;
            uo[j] = f2bf(a + bb);
            vo[j] = f2bf(a - bb);
        }
        *(uint4*)(U + (size_t)r * KD + n0) = *(uint4*)uo;
        *(uint4*)(V + (size_t)r * KD + n0) = *(uint4*)vo;
    } else {
        int id = (blockIdx.x - UV_BLOCKS) * 256 + tid; // [0, 2048*128)
        int c  = id >> 7;                              // basis row 0..2047
        int n0 = (id & 127) * 8;
        int cls = c >> 9, g = c & 511;
        int f = 2 * g + (cls & 1);
        ushort o[8];
        const float step = 6.28318530717958648f / 2048.f;
#pragma unroll
        for (int j = 0; j < 8; ++j) {
            int m = (f * (n0 + j)) & 2047;             // exact reduction
            float th = step * (float)m;
            float val = (cls < 2) ? __cosf(th) : -__sinf(th);
            o[j] = f2bf(val);
        }
        *(uint4*)(bt + (size_t)c * KD + n0) = *(uint4*)o;
    }
}

// ---------------------------------------------------------------------------
// GEMM: for each class (re-even / re-odd / im-even / im-odd):
//   C[4032, 512] = A(U or V)[4032,1024] * basis_cls^T, bf16 in, fp32 acc/out.
// ntile 0..15: cls = ntile&3, ctile = ntile>>2 (128-col block within 512).
// 32x32x16 MFMA, R7-verified XOR-swizzled global_load_lds staging, BK=64.
// LDS per half: [128 rows][32 elems]; chunk c of row r at pos c^((r>>1)&3).
//
// T3/T4 pipeline (guide §5.5): LDS double-buffered (2x16KB A + 2x16KB B),
// tile kt+1 prefetched via global_load_lds while tile kt computes; raw
// s_barrier + counted `s_waitcnt vmcnt(8)` (the 8 prefetch loads stay in
// flight across the barrier — never drain to 0 in the main loop).
// ---------------------------------------------------------------------------
__device__ __forceinline__ void gload16(const ushort* g, ushort* l) {
    __builtin_amdgcn_global_load_lds(
        (const __attribute__((address_space(1))) unsigned int*)g,
        (__attribute__((address_space(3))) unsigned int*)l,
        16, 0, 0);
}

__global__ __launch_bounds__(256) void stft_gemm(
    const ushort* __restrict__ U, const ushort* __restrict__ V,
    const ushort* __restrict__ bt, float* __restrict__ out) {
    // [buf][khalf][128 rows][32 elems] : 2*2*128*32*2B = 32 KB each
    __shared__ __align__(16) ushort As[2 * 8192];
    __shared__ __align__(16) ushort Bs[2 * 8192];

    const int tid  = threadIdx.x;
    const int lane = tid & 63;
    const int w    = tid >> 6;                         // wave 0..3
    const int mtile = blockIdx.x;                      // 0..31 (32nd = M-tail)
    const int ntile = blockIdx.y;                      // 0..15
    const int cls   = ntile & 3;                       // output class
    const int ctile = ntile >> 2;                      // 128-col block in [0,512)

    // --- staging (R7-verified): wave w stages rows [w*16, w*16+16) ---
    const int srow = w * 16 + (lane >> 2);             // 0..63
    const int kcol = ((lane & 3) ^ ((lane >> 3) & 3)) * 8;

    const ushort* Apt = (cls & 1) ? V : U;
    int gr0 = mtile * BM + srow;
    int gr1 = gr0 + 64;
    gr0 = min(gr0, M_TOTAL - 1);                       // clamp M-tail (stores masked)
    gr1 = min(gr1, M_TOTAL - 1);
    const ushort* gA0 = Apt + (size_t)gr0 * KD + kcol;
    const ushort* gA1 = Apt + (size_t)gr1 * KD + kcol;
    const ushort* gB0 = bt + (size_t)(cls * 512 + ctile * BN + srow) * KD + kcol;
    const ushort* gB1 = gB0 + (size_t)64 * KD;

    // --- fragment addressing (32x32 operand: m=lane&31, k=(lane>>5)*8+j) ---
    const int wm = w >> 1, wn = w & 1;                 // wave -> 64x64 quadrant
    const int fr32 = lane & 31;
    const int kg   = lane >> 5;                        // k-group 0/1
    const int rsw  = (fr32 >> 1) & 3;                  // row swizzle bits
    const ushort* pA = As + (wm * 64 + fr32) * 32;
    const ushort* pB = Bs + (wn * 64 + fr32) * 32;

    floatx16 acc[2][2];
#pragma unroll
    for (int mi = 0; mi < 2; ++mi)
#pragma unroll
        for (int ni = 0; ni < 2; ++ni)
#pragma unroll
            for (int r = 0; r < 16; ++r) acc[mi][ni][r] = 0.f;

    // issue 8 gload16 for one BK=64 tile into buffer `buf`, advance pointers
    auto STAGE = [&](int buf) {
        ushort* Ab = As + buf * 8192 + w * 512;        // wave-uniform bases
        ushort* Bb = Bs + buf * 8192 + w * 512;
        gload16(gA0,      Ab);
        gload16(gA0 + 32, Ab + 4096);                  // k-half 1
        gload16(gA1,      Ab + 2048);                  // rows 64..127
        gload16(gA1 + 32, Ab + 6144);
        gload16(gB0,      Bb);
        gload16(gB0 + 32, Bb + 4096);
        gload16(gB1,      Bb + 2048);
        gload16(gB1 + 32, Bb + 6144);
        gA0 += BK; gA1 += BK; gB0 += BK; gB1 += BK;
    };

    auto COMPUTE = [&](int buf) {
        const int bo = buf * 8192;
#pragma unroll
        for (int s = 0; s < 4; ++s) {                  // 4 k-steps of 16
            const int off = bo + (s >> 1) * 4096 + (((s & 1) * 2 + kg) ^ rsw) * 8;
            short8 a[2], b[2];
#pragma unroll
            for (int mi = 0; mi < 2; ++mi)
                a[mi] = *(const short8*)(pA + mi * 32 * 32 + off);
#pragma unroll
            for (int ni = 0; ni < 2; ++ni)
                b[ni] = *(const short8*)(pB + ni * 32 * 32 + off);
            __builtin_amdgcn_s_setprio(1);
#pragma unroll
            for (int mi = 0; mi < 2; ++mi)
#pragma unroll
                for (int ni = 0; ni < 2; ++ni)
                    acc[mi][ni] = __builtin_amdgcn_mfma_f32_32x32x16_bf16(
                        a[mi], b[ni], acc[mi][ni], 0, 0, 0);
            __builtin_amdgcn_s_setprio(0);
        }
    };

    STAGE(0);                                          // tile 0 -> buf0
    for (int kt = 0; kt < KD / BK - 1; ++kt) {         // 15 pipelined iters
        const int cur = kt & 1;
        STAGE(cur ^ 1);                                // prefetch tile kt+1
        // wait only for tile kt's 8 loads (the 8 just-issued stay in flight)
        asm volatile("s_waitcnt vmcnt(8)" ::: "memory");
        __builtin_amdgcn_sched_barrier(0);
        __builtin_amdgcn_s_barrier();                  // all waves: buf[cur] ready
        __builtin_amdgcn_sched_barrier(0);
        COMPUTE(cur);
        // all ds_reads of buf[cur] delivered before anyone overwrites it
        asm volatile("s_waitcnt lgkmcnt(0)" ::: "memory");
        __builtin_amdgcn_sched_barrier(0);
        __builtin_amdgcn_s_barrier();
        __builtin_amdgcn_sched_barrier(0);
    }
    asm volatile("s_waitcnt vmcnt(0)" ::: "memory");   // drain last tile
    __builtin_amdgcn_sched_barrier(0);
    __builtin_amdgcn_s_barrier();
    __builtin_amdgcn_sched_barrier(0);
    COMPUTE(1);                                        // tile 15 (15&1 = 1)

    // --- epilogue: C/D col=lane&31, row=(reg&3)+8*(reg>>2)+4*(lane>>5) ---
    // output bin f = 2*g + (cls&1), g = ctile*128 + wn*64 + fr32 + ni*32
    const int orow_base = mtile * BM + wm * 64;
    float* outp = out + (size_t)(cls >> 1) * M_TOTAL * FREQ;
    const int fbase = 2 * (ctile * BN + wn * 64 + fr32) + (cls & 1);

#pragma unroll
    for (int mi = 0; mi < 2; ++mi) {
#pragma unroll
        for (int r = 0; r < 16; ++r) {
            int grow = orow_base + mi * 32 + (r & 3) + 8 * (r >> 2) + 4 * kg;
            if (grow < M_TOTAL) {
                float* orow = outp + (size_t)grow * FREQ + fbase;
#pragma unroll
                for (int ni = 0; ni < 2; ++ni)
                    orow[ni * 64] = acc[mi][ni][r];
            }
        }
    }
}

extern "C" void kernel_launch(void* const* d_in, const int* in_sizes, int n_in,
                              void* d_out, int out_size, void* d_ws, size_t ws_size,
                              hipStream_t stream) {
    const float* x = (const float*)d_in[0];    // fp32 [64, 32256, 1]
    // d_in[1]/d_in[2] (basis) unused: regenerated analytically (deterministic)

    ushort* U   = (ushort*)d_ws;                               // 4032*1024 bf16
    ushort* V   = U + (size_t)M_TOTAL * KD;                    // 4032*1024 bf16
    ushort* btm = V + (size_t)M_TOTAL * KD;                    // 2048*1024 bf16

    prep_fused<<<UV_BLOCKS + BASIS_BLOCKS, 256, 0, stream>>>(x, U, V, btm);
    stft_gemm<<<dim3((M_TOTAL + BM - 1) / BM, 16), 256, 0, stream>>>(
        U, V, btm, (float*)d_out);
}

// Round 2
// 105.087 us; speedup vs baseline: 1.0337x; 1.0337x over previous
//
#include <hip/hip_runtime.h>
#include <hip/hip_bf16.h>
#include <math.h>

#define WINDOW   2048
#define STRIDE   512
#define FREQ     1024
#define FRAMES   63
#define SIG_LEN  32256
#define BATCH    64
#define M_TOTAL  4032             // BATCH*FRAMES
#define KD       1024             // decimated K (one radix-2 DIF stage)

#define BM 128
#define BN 128
#define BK 64                     // two 32-wide half-buffers

#define UV_BLOCKS    2016         // 4032*128/256
#define BASIS_BLOCKS 1024         // 2048*128/256

typedef __attribute__((ext_vector_type(8)))  short short8;    // 8 bf16
typedef __attribute__((ext_vector_type(16))) float floatx16;  // 32x32 acc

__device__ __forceinline__ ushort f2bf(float f) {
    __hip_bfloat16 h = __float2bfloat16(f);
    return *reinterpret_cast<ushort*>(&h);
}

// ---------------------------------------------------------------------------
// Fused prep, single dispatch.
// Blocks [0,2016): build U,V (radix-2 DIF of the windowed frames):
//   xw[r][n] = x[b][t*512+n-768]*hann[n] (0 out of range), r=b*63+t, n<2048
//   U[r][n] = xw[n]+xw[n+1024],  V[r][n] = xw[n]-xw[n+1024],  n<1024
//   hann identity: w[n+1024] = 1 - w[n]  (cos(th+pi) = -cos th) -> one cos.
// Blocks [2016,3040): build basis Bt2[2048][1024] bf16, K-contiguous rows:
//   row c = cls*512+g: cls0: cos(2*pi*(2g)n/2048)   cls1: cos(2*pi*(2g+1)n/2048)
//                      cls2: -sin(2*pi*(2g)n/2048)  cls3: -sin(2*pi*(2g+1)n/2048)
//   (= cos/sin of the reference phase; exact int reduction (f*n)&2047)
// ---------------------------------------------------------------------------
__global__ __launch_bounds__(256) void prep_fused(
    const float* __restrict__ x, ushort* __restrict__ U,
    ushort* __restrict__ V, ushort* __restrict__ bt) {
    const int tid = threadIdx.x;
    if (blockIdx.x < UV_BLOCKS) {
        int id = blockIdx.x * 256 + tid;               // [0, 4032*128)
        int r  = id >> 7;                              // row 0..4031
        int n0 = (id & 127) * 8;                       // n offset, mult of 8
        int b  = r / FRAMES, t = r - b * FRAMES;
        int p0 = t * STRIDE + n0 - 768;                // mult of 8
        int p1 = p0 + 1024;
        float x0[8] = {0,0,0,0,0,0,0,0}, x1[8] = {0,0,0,0,0,0,0,0};
        const float* xb = x + (size_t)b * SIG_LEN;
        if (p0 >= 0 && p0 + 8 <= SIG_LEN) {
            float4 a = *(const float4*)(xb + p0), c = *(const float4*)(xb + p0 + 4);
            x0[0]=a.x; x0[1]=a.y; x0[2]=a.z; x0[3]=a.w;
            x0[4]=c.x; x0[5]=c.y; x0[6]=c.z; x0[7]=c.w;
        }
        if (p1 >= 0 && p1 + 8 <= SIG_LEN) {
            float4 a = *(const float4*)(xb + p1), c = *(const float4*)(xb + p1 + 4);
            x1[0]=a.x; x1[1]=a.y; x1[2]=a.z; x1[3]=a.w;
            x1[4]=c.x; x1[5]=c.y; x1[6]=c.z; x1[7]=c.w;
        }
        ushort uo[8], vo[8];
        const float c0 = 6.28318530717958648f / 2048.f;
#pragma unroll
        for (int j = 0; j < 8; ++j) {
            int n = n0 + j;
            float cn = __cosf(c0 * (float)n);
            float w0 = 0.5f - 0.5f * cn;               // hann[n]
            float w1 = 0.5f + 0.5f * cn;               // hann[n+1024] = 1-hann[n]
            float a = x0[j] * w0, bb = x1[j] * w1;
            uo[j] = f2bf(a + bb);
            vo[j] = f2bf(a - bb);
        }
        *(uint4*)(U + (size_t)r * KD + n0) = *(uint4*)uo;
        *(uint4*)(V + (size_t)r * KD + n0) = *(uint4*)vo;
    } else {
        int id = (blockIdx.x - UV_BLOCKS) * 256 + tid; // [0, 2048*128)
        int c  = id >> 7;                              // basis row 0..2047
        int n0 = (id & 127) * 8;
        int cls = c >> 9, g = c & 511;
        int f = 2 * g + (cls & 1);
        ushort o[8];
        const float step = 6.28318530717958648f / 2048.f;
#pragma unroll
        for (int j = 0; j < 8; ++j) {
            int m = (f * (n0 + j)) & 2047;             // exact reduction
            float th = step * (float)m;
            float val = (cls < 2) ? __cosf(th) : -__sinf(th);
            o[j] = f2bf(val);
        }
        *(uint4*)(bt + (size_t)c * KD + n0) = *(uint4*)o;
    }
}

// ---------------------------------------------------------------------------
// GEMM: for each class (re-even / re-odd / im-even / im-odd):
//   C[4032, 512] = A(U or V)[4032,1024] * basis_cls^T, bf16 in, fp32 acc/out.
// ntile 0..15: cls = ntile&3, ctile = ntile>>2 (128-col block within 512).
// 32x32x16 MFMA, R7-verified XOR-swizzled global_load_lds staging, BK=64.
// LDS per half: [128 rows][32 elems]; chunk c of row r at pos c^((r>>1)&3).
// (R0 2-barrier structure restored: the R1 explicit pipeline was -2.4 us at
//  this kernel scale — Common Mistake #5; implicit wave overlap suffices.)
// ---------------------------------------------------------------------------
__device__ __forceinline__ void gload16(const ushort* g, ushort* l) {
    __builtin_amdgcn_global_load_lds(
        (const __attribute__((address_space(1))) unsigned int*)g,
        (__attribute__((address_space(3))) unsigned int*)l,
        16, 0, 0);
}

__global__ __launch_bounds__(256) void stft_gemm(
    const ushort* __restrict__ U, const ushort* __restrict__ V,
    const ushort* __restrict__ bt, float* __restrict__ out) {
    __shared__ __align__(16) ushort As[2 * BM * 32];   // 16 KB: [half][128][32]
    __shared__ __align__(16) ushort Bs[2 * BN * 32];   // 16 KB

    const int tid  = threadIdx.x;
    const int lane = tid & 63;
    const int w    = tid >> 6;                         // wave 0..3
    const int mtile = blockIdx.x;                      // 0..31 (32nd = M-tail)
    const int ntile = blockIdx.y;                      // 0..15
    const int cls   = ntile & 3;                       // output class
    const int ctile = ntile >> 2;                      // 128-col block in [0,512)

    // --- staging (R7-verified): wave w stages rows [w*16, w*16+16) ---
    const int srow = w * 16 + (lane >> 2);             // 0..63
    const int kcol = ((lane & 3) ^ ((lane >> 3) & 3)) * 8;

    const ushort* Apt = (cls & 1) ? V : U;
    int gr0 = mtile * BM + srow;
    int gr1 = gr0 + 64;
    gr0 = min(gr0, M_TOTAL - 1);                       // clamp M-tail (stores masked)
    gr1 = min(gr1, M_TOTAL - 1);
    const ushort* gA0 = Apt + (size_t)gr0 * KD + kcol;
    const ushort* gA1 = Apt + (size_t)gr1 * KD + kcol;
    const ushort* gB0 = bt + (size_t)(cls * 512 + ctile * BN + srow) * KD + kcol;
    const ushort* gB1 = gB0 + (size_t)64 * KD;

    ushort* ldsA0 = As + w * 512;                      // wave-uniform bases
    ushort* ldsA1 = As + 2048 + w * 512;
    ushort* ldsB0 = Bs + w * 512;
    ushort* ldsB1 = Bs + 2048 + w * 512;

    // --- fragment addressing (32x32 operand: m=lane&31, k=(lane>>5)*8+j) ---
    const int wm = w >> 1, wn = w & 1;                 // wave -> 64x64 quadrant
    const int fr32 = lane & 31;
    const int kg   = lane >> 5;                        // k-group 0/1
    const int rsw  = (fr32 >> 1) & 3;                  // row swizzle bits
    const ushort* pA = As + (wm * 64 + fr32) * 32;
    const ushort* pB = Bs + (wn * 64 + fr32) * 32;

    floatx16 acc[2][2];
#pragma unroll
    for (int mi = 0; mi < 2; ++mi)
#pragma unroll
        for (int ni = 0; ni < 2; ++ni)
#pragma unroll
            for (int r = 0; r < 16; ++r) acc[mi][ni][r] = 0.f;

    for (int kt = 0; kt < KD / BK; ++kt) {             // 16 iters
        __syncthreads();                               // LDS safe to overwrite
        gload16(gA0,      ldsA0);
        gload16(gA0 + 32, ldsA0 + 4096);               // k-half 1
        gload16(gA1,      ldsA1);
        gload16(gA1 + 32, ldsA1 + 4096);
        gload16(gB0,      ldsB0);
        gload16(gB0 + 32, ldsB0 + 4096);
        gload16(gB1,      ldsB1);
        gload16(gB1 + 32, ldsB1 + 4096);
        gA0 += BK; gA1 += BK; gB0 += BK; gB1 += BK;
        __syncthreads();                               // staging complete

#pragma unroll
        for (int s = 0; s < 4; ++s) {                  // 4 k-steps of 16
            const int off = (s >> 1) * 4096 + (((s & 1) * 2 + kg) ^ rsw) * 8;
            short8 a[2], b[2];
#pragma unroll
            for (int mi = 0; mi < 2; ++mi)
                a[mi] = *(const short8*)(pA + mi * 32 * 32 + off);
#pragma unroll
            for (int ni = 0; ni < 2; ++ni)
                b[ni] = *(const short8*)(pB + ni * 32 * 32 + off);
#pragma unroll
            for (int mi = 0; mi < 2; ++mi)
#pragma unroll
                for (int ni = 0; ni < 2; ++ni)
                    acc[mi][ni] = __builtin_amdgcn_mfma_f32_32x32x16_bf16(
                        a[mi], b[ni], acc[mi][ni], 0, 0, 0);
        }
    }

    // --- epilogue: C/D col=lane&31, row=(reg&3)+8*(reg>>2)+4*(lane>>5) ---
    // output bin f = 2*g + (cls&1), g = ctile*128 + wn*64 + fr32 + ni*32
    const int orow_base = mtile * BM + wm * 64;
    float* outp = out + (size_t)(cls >> 1) * M_TOTAL * FREQ;
    const int fbase = 2 * (ctile * BN + wn * 64 + fr32) + (cls & 1);

#pragma unroll
    for (int mi = 0; mi < 2; ++mi) {
#pragma unroll
        for (int r = 0; r < 16; ++r) {
            int grow = orow_base + mi * 32 + (r & 3) + 8 * (r >> 2) + 4 * kg;
            if (grow < M_TOTAL) {
                float* orow = outp + (size_t)grow * FREQ + fbase;
#pragma unroll
                for (int ni = 0; ni < 2; ++ni)
                    orow[ni * 64] = acc[mi][ni][r];
            }
        }
    }
}

extern "C" void kernel_launch(void* const* d_in, const int* in_sizes, int n_in,
                              void* d_out, int out_size, void* d_ws, size_t ws_size,
                              hipStream_t stream) {
    const float* x = (const float*)d_in[0];    // fp32 [64, 32256, 1]
    // d_in[1]/d_in[2] (basis) unused: regenerated analytically (deterministic)

    ushort* U   = (ushort*)d_ws;                               // 4032*1024 bf16
    ushort* V   = U + (size_t)M_TOTAL * KD;                    // 4032*1024 bf16
    ushort* btm = V + (size_t)M_TOTAL * KD;                    // 2048*1024 bf16

    prep_fused<<<UV_BLOCKS + BASIS_BLOCKS, 256, 0, stream>>>(x, U, V, btm);
    stft_gemm<<<dim3((M_TOTAL + BM - 1) / BM, 16), 256, 0, stream>>>(
        U, V, btm, (float*)d_out);
}